// Round 7
// baseline (249.677 us; speedup 1.0000x reference)
//
#include <hip/hip_runtime.h>
#include <cstddef>

#define B_    32
#define N_    1024
#define E_    4096
#define A_    16
#define FIN_  16
#define H_    64
#define MID_  208
#define NODES (B_ * N_)      // 32768
#define NEDGE (B_ * E_)      // 131072
#define ROWS  (B_ * A_ * N_) // 524288
#define AN_   (A_ * N_)      // 16384

typedef __attribute__((ext_vector_type(8))) __bf16 bf16x8;
typedef __attribute__((ext_vector_type(4))) float f32x4;

__device__ __forceinline__ f32x4 mfma16(bf16x8 a, bf16x8 b, f32x4 c) {
  return __builtin_amdgcn_mfma_f32_16x16x32_bf16(a, b, c, 0, 0, 0);
}

// split 8 consecutive fp32 into bf16 hi + lo fragments (error ~2^-18 rel)
__device__ __forceinline__ void cvt8(const float* __restrict__ p, bf16x8& hi, bf16x8& lo) {
  float4 v0 = *(const float4*)p;
  float4 v1 = *(const float4*)(p + 4);
  float vv[8] = {v0.x, v0.y, v0.z, v0.w, v1.x, v1.y, v1.z, v1.w};
#pragma unroll
  for (int i = 0; i < 8; i++) {
    __bf16 h = (__bf16)vv[i];
    hi[i] = h;
    lo[i] = (__bf16)(vv[i] - (float)h);
  }
}

// ---------------- front: CSR + d1 + e1 + cu + W1B^T->bf16 + layer-W^T->bf16 ----------------
__global__ __launch_bounds__(256) void k_front(const int* __restrict__ el,
                                               const float* __restrict__ dist,
                                               const int* __restrict__ loc,
                                               const float* __restrict__ W1,
                                               const float* __restrict__ eW,
                                               const float* __restrict__ eb,
                                               const float* __restrict__ b1,
                                               const float* __restrict__ c0W,
                                               const float* __restrict__ c1W,
                                               const float* __restrict__ c2W,
                                               int* __restrict__ rowptr,
                                               int* __restrict__ counts,
                                               int* __restrict__ ssrc,
                                               float* __restrict__ d1row,
                                               float* __restrict__ c2row,
                                               float* __restrict__ e1,
                                               float* __restrict__ cu,
                                               float* __restrict__ base,
                                               __bf16* __restrict__ W1BTh,
                                               __bf16* __restrict__ W1BTl,
                                               __bf16* __restrict__ WTh,
                                               __bf16* __restrict__ WTl) {
  __shared__ int cnt[1024];
  __shared__ int cur[1024];
  __shared__ int part[256];
  __shared__ int ssrcS[4096];
  __shared__ int loc_s[16];
  int blk = blockIdx.x, t = threadIdx.x;
  if (blk < 32) {
    int b = blk;
    for (int i = t; i < 1024; i += 256) cnt[i] = 0;
    __syncthreads();
    const int* srcp = el + b * (2 * E_);
    const int* dstp = srcp + E_;
    for (int i = t; i < E_; i += 256) atomicAdd(&cnt[dstp[i]], 1);
    __syncthreads();
    int4 c4 = *(const int4*)&cnt[t * 4];
    int s = c4.x + c4.y + c4.z + c4.w;
    part[t] = s;
    __syncthreads();
    for (int off = 1; off < 256; off <<= 1) {
      int v = (t >= off) ? part[t - off] : 0;
      __syncthreads();
      part[t] += v;
      __syncthreads();
    }
    int prev = (t == 0) ? 0 : part[t - 1];
    int p0 = prev, p1 = p0 + c4.x, p2 = p1 + c4.y, p3 = p2 + c4.z;
    *(int4*)&rowptr[b * 1024 + t * 4] = make_int4(p0 + b * E_, p1 + b * E_, p2 + b * E_, p3 + b * E_);
    *(int4*)&counts[b * 1024 + t * 4] = c4;
    cur[t * 4 + 0] = p0;
    cur[t * 4 + 1] = p1;
    cur[t * 4 + 2] = p2;
    cur[t * 4 + 3] = p3;
    __syncthreads();
    for (int i = t; i < E_; i += 256) {
      int dl = dstp[i];
      int sl = srcp[i];
      int pos = atomicAdd(&cur[dl], 1);
      ssrcS[pos] = b * N_ + sl;
    }
    __syncthreads();
    for (int i = t; i < E_; i += 256) ssrc[b * E_ + i] = ssrcS[i];
  } else if (blk < 288) {
    int lane = t & 63, w = t >> 6;
    int r = (blk - 32) * 4 + w;
    const float* dr = dist + (size_t)r * N_;
    float s = 0.f, c2 = 0.f;
#pragma unroll
    for (int k = 0; k < 16; k++) {
      float v = dr[lane + 64 * k];
      s += v;
      c2 = fmaf(v, v, c2);
    }
#pragma unroll
    for (int o = 32; o > 0; o >>= 1) { s += __shfl_xor(s, o); c2 += __shfl_xor(c2, o); }
    if (lane == 0) { d1row[r] = s; c2row[r] = c2; }
  } else if (blk < 320) {
    int b = blk - 288;
    if (t < 16) loc_s[t] = loc[b * 16 + t];
    __syncthreads();
    float e4[4] = {0.f, 0.f, 0.f, 0.f};
    for (int a = 0; a < 16; a++) {
      const float* dr = dist + (size_t)loc_s[a] * N_;
#pragma unroll
      for (int k = 0; k < 4; k++) e4[k] += dr[t + 256 * k];
    }
#pragma unroll
    for (int k = 0; k < 4; k++) e1[b * N_ + t + 256 * k] = e4[k];
  } else if (blk == 320) {
    int j = t;
    if (j < MID_) {
      float c = 0.f, bs = 0.f;
      for (int k = 0; k < H_; k++) {
        float w = W1[(2 * MID_ + k) * MID_ + j];
        c = fmaf(eW[k], w, c);
        bs = fmaf(eb[k], w, bs);
      }
      cu[j] = c;
      base[j] = bs + b1[j];
    }
  } else if (blk < 529) {
    // W1B^T conversion to bf16 hi/lo, row j = blk-321, k padded to 224 with zeros
    int jr = blk - 321;
    if (t < 224) {
      float v = (t < MID_) ? W1[(size_t)(MID_ + t) * MID_ + jr] : 0.f;
      __bf16 h = (__bf16)v;
      W1BTh[jr * 224 + t] = h;
      W1BTl[jr * 224 + t] = (__bf16)(v - (float)h);
    }
  } else {
    // blk 529..531: layer-l W^T bf16 hi/lo, 64 j x 64 k.
    // layer0 (16 input feats): k-replicated 4x so that K=64 channel-partial agg works.
    int l = blk - 529;
    const float* Wsrc = (l == 0) ? c0W : (l == 1) ? c1W : c2W;
    int fmask = (l == 0) ? 15 : 63;
    for (int i = t; i < 4096; i += 256) {
      int j = i >> 6, k = i & 63;
      float v = Wsrc[(k & fmask) * 64 + j];
      __bf16 h = (__bf16)v;
      WTh[l * 4096 + j * 64 + k] = h;
      WTl[l * 4096 + j * 64 + k] = (__bf16)(v - (float)h);
    }
  }
}

// ---------------- GIN layer (MFMA): wave = 16 nodes, all 64 j; 64 nodes/block ----------------
// Gather agg per lane (k-slot = lane: for FIN=16 this is channel ch=lane>>4, feat f=lane&15 —
// the W^T was k-replicated to match). Stage to wave-private LDS [16][68] (stride 68 -> 2-way
// bank alias only). MFMA D layout: col=lane&15 (node), row=(lane>>4)*4+reg (j) — all 64 j of a
// node live in one lane column => LN = 16 local adds + shfl_xor(16,32).
template <int FINT, bool COPYIN>
__global__ __launch_bounds__(256) void k_layer(const float* __restrict__ xin, int xstride, int in_off,
                                               float* __restrict__ xc, int out_off,
                                               const int* __restrict__ rowptr,
                                               const int* __restrict__ counts,
                                               const int* __restrict__ ssrc,
                                               const __bf16* __restrict__ WTh,
                                               const __bf16* __restrict__ WTl,
                                               const float* __restrict__ bias,
                                               const float* __restrict__ g,
                                               const float* __restrict__ beta) {
  __shared__ float aggS[4][16][68];
  int t = threadIdx.x, lane = t & 63, w = t >> 6;
  constexpr int CH = 64 / FINT;
  int f = lane & (FINT - 1);
  int ch = (FINT == 64) ? 0 : (lane >> 4);
  int blk = blockIdx.x;
  int xcd = blk & 7, kk = blk >> 3;           // 512 blocks: 64 per xcd
  int graph = xcd * 4 + (kk >> 4);
  int nblk = kk & 15;
  int tilebase = graph * N_ + nblk * 64 + w * 16;

  float aggv[16];
#pragma unroll
  for (int nn = 0; nn < 16; nn++) {
    int node = tilebase + nn;
    int r0 = rowptr[node];
    int deg = counts[node];
    float a0 = 0.f, a1 = 0.f, a2 = 0.f, a3 = 0.f;
    int e = ch;
    for (; e + 3 * CH < deg; e += 4 * CH) {
      int s0 = ssrc[r0 + e];
      int s1 = ssrc[r0 + e + CH];
      int s2 = ssrc[r0 + e + 2 * CH];
      int s3 = ssrc[r0 + e + 3 * CH];
      a0 += xin[(size_t)s0 * xstride + in_off + f];
      a1 += xin[(size_t)s1 * xstride + in_off + f];
      a2 += xin[(size_t)s2 * xstride + in_off + f];
      a3 += xin[(size_t)s3 * xstride + in_off + f];
    }
    for (; e < deg; e += CH) {
      int s = ssrc[r0 + e];
      a0 += xin[(size_t)s * xstride + in_off + f];
    }
    aggv[nn] = (a0 + a1) + (a2 + a3);
  }
#pragma unroll
  for (int nn = 0; nn < 16; nn++) aggS[w][nn][lane] = aggv[nn];
  // wave-private LDS region: no barrier needed; compiler inserts lgkmcnt waits.

  int q = lane >> 4, li = lane & 15;
  bf16x8 bh[2], bl[2];
#pragma unroll
  for (int ks = 0; ks < 2; ks++) cvt8(&aggS[w][li][ks * 32 + q * 8], bh[ks], bl[ks]);

  f32x4 zero4 = {0.f, 0.f, 0.f, 0.f};
  f32x4 acc[4];
#pragma unroll
  for (int jt = 0; jt < 4; jt++) {
    acc[jt] = zero4;
#pragma unroll
    for (int ks = 0; ks < 2; ks++) {
      bf16x8 ah = *(const bf16x8*)(WTh + (size_t)(jt * 16 + li) * 64 + ks * 32 + q * 8);
      bf16x8 al = *(const bf16x8*)(WTl + (size_t)(jt * 16 + li) * 64 + ks * 32 + q * 8);
      acc[jt] = mfma16(ah, bh[ks], acc[jt]);
      acc[jt] = mfma16(ah, bl[ks], acc[jt]);
      acc[jt] = mfma16(al, bh[ks], acc[jt]);
    }
  }

  // bias, then LayerNorm over the node's 64 j (16 local + cross-q shuffles)
  float y[16];
#pragma unroll
  for (int jt = 0; jt < 4; jt++) {
    float4 b4 = *(const float4*)(bias + jt * 16 + q * 4);
    y[jt * 4 + 0] = acc[jt][0] + b4.x;
    y[jt * 4 + 1] = acc[jt][1] + b4.y;
    y[jt * 4 + 2] = acc[jt][2] + b4.z;
    y[jt * 4 + 3] = acc[jt][3] + b4.w;
  }
  float s = 0.f;
#pragma unroll
  for (int i = 0; i < 16; i++) s += y[i];
  s += __shfl_xor(s, 16);
  s += __shfl_xor(s, 32);
  float m = s * (1.f / 64.f);
  float vv = 0.f;
#pragma unroll
  for (int i = 0; i < 16; i++) {
    float d = y[i] - m;
    vv = fmaf(d, d, vv);
  }
  vv += __shfl_xor(vv, 16);
  vv += __shfl_xor(vv, 32);
  float rs = rsqrtf(vv * (1.f / 64.f) + 1e-5f);

  size_t node = tilebase + li;
  float* xrow = xc + node * MID_ + out_off;
#pragma unroll
  for (int jt = 0; jt < 4; jt++) {
    float4 g4 = *(const float4*)(g + jt * 16 + q * 4);
    float4 be4 = *(const float4*)(beta + jt * 16 + q * 4);
    float4 o;
    o.x = fmaxf((y[jt * 4 + 0] - m) * rs * g4.x + be4.x, 0.f);
    o.y = fmaxf((y[jt * 4 + 1] - m) * rs * g4.y + be4.y, 0.f);
    o.z = fmaxf((y[jt * 4 + 2] - m) * rs * g4.z + be4.z, 0.f);
    o.w = fmaxf((y[jt * 4 + 3] - m) * rs * g4.w + be4.w, 0.f);
    *(float4*)(xrow + jt * 16 + q * 4) = o;
  }
  if (COPYIN) {
    float4 v = *(const float4*)(xin + node * FIN_ + q * 4);
    *(float4*)(xc + node * MID_ + q * 4) = v;
  }
}

// ---------------- p1: blk<1024: MFMA GEMM pBT (bf16 hi/lo split) + in-register column stats; blk>=1024: pA ----------------
__global__ __launch_bounds__(256) void k_p1(const float* __restrict__ xc,
                                            const float* __restrict__ W1,
                                            const __bf16* __restrict__ W1BTh,
                                            const __bf16* __restrict__ W1BTl,
                                            const float* __restrict__ e1,
                                            const int* __restrict__ loc,
                                            float* __restrict__ pBT,
                                            float* __restrict__ pA,
                                            float* __restrict__ SB1,
                                            float* __restrict__ SB2,
                                            float* __restrict__ SB3) {
  __shared__ float xr[MID_];
  int t = threadIdx.x, lane = t & 63;
  int w = t >> 6;
  int blk = blockIdx.x;
  if (blk < 1024) {
    int nb = blk * 32;
    int q = lane >> 4, li = lane & 15;
    int jt0 = (w == 0) ? 0 : (w == 1) ? 4 : (w == 2) ? 7 : 10;
    int njt = (w == 0) ? 4 : 3;
    f32x4 zero4 = {0.f, 0.f, 0.f, 0.f};
    f32x4 acc0[4], acc1[4];
#pragma unroll
    for (int i = 0; i < 4; i++) { acc0[i] = zero4; acc1[i] = zero4; }
    const float* xr0 = xc + (size_t)(nb + li) * MID_;
    const float* xr1 = xc + (size_t)(nb + 16 + li) * MID_;
    for (int kc = 0; kc < 7; kc++) {
      int k0 = kc * 32 + q * 8;
      bf16x8 b0h, b0l, b1h, b1l;
      if (k0 < MID_) {
        cvt8(xr0 + k0, b0h, b0l);
        cvt8(xr1 + k0, b1h, b1l);
      } else {
#pragma unroll
        for (int i = 0; i < 8; i++) {
          b0h[i] = (__bf16)0.f; b0l[i] = (__bf16)0.f;
          b1h[i] = (__bf16)0.f; b1l[i] = (__bf16)0.f;
        }
      }
#pragma unroll
      for (int jj = 0; jj < 4; jj++) {
        if (jj < njt) {
          int jt = jt0 + jj;
          bf16x8 ah = *(const bf16x8*)(W1BTh + (size_t)(jt * 16 + li) * 224 + k0);
          bf16x8 al = *(const bf16x8*)(W1BTl + (size_t)(jt * 16 + li) * 224 + k0);
          acc0[jj] = mfma16(ah, b0h, acc0[jj]);
          acc0[jj] = mfma16(ah, b0l, acc0[jj]);
          acc0[jj] = mfma16(al, b0h, acc0[jj]);
          acc1[jj] = mfma16(ah, b1h, acc1[jj]);
          acc1[jj] = mfma16(ah, b1l, acc1[jj]);
          acc1[jj] = mfma16(al, b1h, acc1[jj]);
        }
      }
    }
    float ev0 = e1[nb + li];
    float ev1 = e1[nb + 16 + li];
#pragma unroll
    for (int jj = 0; jj < 4; jj++) {
      if (jj < njt) {
        int jt = jt0 + jj;
#pragma unroll
        for (int r = 0; r < 4; r++) {
          int j = jt * 16 + q * 4 + r;
          float* pb = pBT + (size_t)j * NODES + nb + li;
          pb[0] = acc0[jj][r];
          pb[16] = acc1[jj][r];
        }
        float s1v[4], s2v[4], s3v[4];
#pragma unroll
        for (int r = 0; r < 4; r++) {
          float a0 = acc0[jj][r], a1 = acc1[jj][r];
          s1v[r] = a0 + a1;
          s2v[r] = fmaf(a0, a0, a1 * a1);
          s3v[r] = fmaf(a0, ev0, a1 * ev1);
        }
#pragma unroll
        for (int o = 8; o > 0; o >>= 1) {
#pragma unroll
          for (int r = 0; r < 4; r++) {
            s1v[r] += __shfl_xor(s1v[r], o);
            s2v[r] += __shfl_xor(s2v[r], o);
            s3v[r] += __shfl_xor(s3v[r], o);
          }
        }
        if (li < 4) {
          float g1 = (li == 0) ? s1v[0] : (li == 1) ? s1v[1] : (li == 2) ? s1v[2] : s1v[3];
          float g2 = (li == 0) ? s2v[0] : (li == 1) ? s2v[1] : (li == 2) ? s2v[2] : s2v[3];
          float g3 = (li == 0) ? s3v[0] : (li == 1) ? s3v[1] : (li == 2) ? s3v[2] : s3v[3];
          int j = jt * 16 + q * 4 + li;
          SB1[(size_t)blk * MID_ + j] = g1;
          SB2[(size_t)blk * MID_ + j] = g2;
          SB3[(size_t)blk * MID_ + j] = g3;
        }
      }
    }
  } else {
    int ab = blk - 1024;           // b*16 + a
    int b = ab >> 4;
    int node = b * N_ + loc[ab];
    for (int i = t; i < MID_; i += 256) xr[i] = xc[(size_t)node * MID_ + i];
    __syncthreads();
    if (t < MID_) {
      float acc = 0.f;
      for (int i = 0; i < MID_; i++) acc = fmaf(xr[i], W1[i * MID_ + t], acc);
      pA[ab * MID_ + t] = acc;
    }
  }
}

// ---------------- fin: one block per feature j — stats from SB partials + BN finalize + vaT + wpack ----------------
__global__ __launch_bounds__(256) void k_fin(const float* __restrict__ SB1,
                                             const float* __restrict__ SB2,
                                             const float* __restrict__ SB3,
                                             const float* __restrict__ pA,
                                             const float* __restrict__ cu,
                                             const float* __restrict__ base,
                                             const float* __restrict__ d1row,
                                             const float* __restrict__ c2row,
                                             const int* __restrict__ loc,
                                             const float* __restrict__ bng,
                                             const float* __restrict__ bnb,
                                             const float* __restrict__ W2,
                                             float* __restrict__ vaT,
                                             float* __restrict__ wpack4) {
  __shared__ float utmp[1536 + 192];
  __shared__ float redm[4];
  __shared__ float reds[4];
  __shared__ float bcast[2];
  int t = threadIdx.x, lane = t & 63, w = t >> 6;
  int j = blockIdx.x;
  float cuj = cu[j], bj = base[j];
  float q1 = 0.f, q2 = 0.f, q3 = 0.f;
#pragma unroll
  for (int c = t * 4; c < t * 4 + 4; c++) {
    q1 += SB1[(size_t)c * MID_ + j];
    q2 += SB2[(size_t)c * MID_ + j];
    q3 += SB3[(size_t)c * MID_ + j];
  }
  float t1 = 0.f, t2 = 0.f, t3 = 0.f;
#pragma unroll
  for (int r = t * 2; r < t * 2 + 2; r++) {
    float pa = pA[r * MID_ + j] + bj;
    t1 += pa;
    t2 = fmaf(pa, pa, t2);
    t3 = fmaf(pa, d1row[loc[r]], t3);
  }
  utmp[0 * 256 + t] = q1;
  utmp[1 * 256 + t] = q2;
  utmp[2 * 256 + t] = q3;
  utmp[3 * 256 + t] = t1;
  utmp[4 * 256 + t] = t2;
  utmp[5 * 256 + t] = t3;
  float p1 = 0.f, p2 = 0.f;
#pragma unroll
  for (int r = t * 2; r < t * 2 + 2; r++) {
    int l = loc[r];
    p1 += d1row[l];
    p2 += c2row[l];
  }
#pragma unroll
  for (int o = 32; o > 0; o >>= 1) { p1 += __shfl_xor(p1, o); p2 += __shfl_xor(p2, o); }
  if (lane == 0) { redm[w] = p1; reds[w] = p2; }
  __syncthreads();
  if (t < 192) {
    int s = t >> 5, b32 = t & 31;
    float ssum = 0.f;
#pragma unroll
    for (int i = 0; i < 8; i++) ssum += utmp[s * 256 + b32 * 8 + i];
    utmp[1536 + s * 32 + b32] = ssum;
  }
  __syncthreads();
  if (t == 0) {
    float Sc1 = (redm[0] + redm[1]) + (redm[2] + redm[3]);
    float Sc2 = (reds[0] + reds[1]) + (reds[2] + reds[3]);
    double T1 = 0, T2 = 0, T3 = 0, cross = 0, sp1 = 0, sp2 = 0, spe = 0;
    for (int b = 0; b < 32; b++) {
      float sq1 = utmp[1536 + 0 * 32 + b];
      float sq2 = utmp[1536 + 1 * 32 + b];
      float sq3 = utmp[1536 + 2 * 32 + b];
      float pt1 = utmp[1536 + 3 * 32 + b];
      float pt2 = utmp[1536 + 4 * 32 + b];
      float pt3 = utmp[1536 + 5 * 32 + b];
      T1 += pt1; T2 += pt2; T3 += pt3;
      cross += (double)pt1 * sq1;
      sp1 += sq1; sp2 += sq2; spe += sq3;
    }
    double s1 = 1024.0 * T1 + 16.0 * sp1 + (double)cuj * Sc1;
    double s2 = 1024.0 * T2 + 16.0 * sp2 + (double)cuj * cuj * Sc2 +
                2.0 * (cross + (double)cuj * (T3 + spe));
    double mu = s1 * (1.0 / (double)ROWS);
    double var = s2 * (1.0 / (double)ROWS) - mu * mu;
    float sc = (float)(1.0 / sqrt(var + 1e-5)) * bng[j];
    float sh = bnb[j] - (float)mu * sc;
    bcast[0] = sc;
    bcast[1] = sh;
    wpack4[4 * j + 0] = sc;
    wpack4[4 * j + 1] = cuj * sc;
    wpack4[4 * j + 2] = W2[j];
    wpack4[4 * j + 3] = 0.f;
  }
  __syncthreads();
  float sc = bcast[0], sh = bcast[1];
#pragma unroll
  for (int r = t * 2; r < t * 2 + 2; r++) {
    int b = r >> 4, a = r & 15;
    float pa = pA[r * MID_ + j] + bj;
    vaT[((size_t)b * MID_ + j) * 16 + a] = pa * sc + sh;
  }
}

// ---------------- logits: 512 threads (8 waves x 26 j's); + softmax partials ----------------
__global__ __launch_bounds__(512) void k_logits(const float* __restrict__ pBT,
                                                const float* __restrict__ vaT,
                                                const float* __restrict__ wpack4,
                                                const float* __restrict__ dist,
                                                const int* __restrict__ loc,
                                                const int* __restrict__ mask,
                                                const float* __restrict__ b2,
                                                float* __restrict__ lg,
                                                float2* __restrict__ Psm) {
  __shared__ float vaS[MID_ * 16];
  __shared__ float accL[8][8][64];
  __shared__ int loc_s[16];
  __shared__ float redm[8];
  __shared__ float reds[8];
  int t = threadIdx.x, lane = t & 63;
  int w = __builtin_amdgcn_readfirstlane(t >> 6);   // 0..7
  int b = blockIdx.y, nt = blockIdx.x;
  int n0 = nt * 64;
  if (t < 16) loc_s[t] = loc[b * 16 + t];
  for (int i = t; i < MID_ * 16; i += 512) vaS[i] = vaT[(size_t)b * MID_ * 16 + i];
  __syncthreads();
  float c[16];
#pragma unroll
  for (int a = 0; a < 16; a++) c[a] = dist[(size_t)loc_s[a] * N_ + n0 + lane];
  float acc16[16];
#pragma unroll
  for (int a = 0; a < 16; a++) acc16[a] = 0.f;
  const float4* wp = (const float4*)wpack4;
  int ng = b * N_ + n0 + lane;
  int jb = w * 26;
#pragma unroll 2
  for (int jj = 0; jj < 26; jj++) {
    int j = jb + jj;
    float pbv = pBT[(size_t)j * NODES + ng];
    float4 wv = wp[j];
    float pbs = pbv * wv.x;
    const float* va = &vaS[j * 16];
#pragma unroll
    for (int a = 0; a < 16; a++) {
      float h = fmaf(c[a], wv.y, va[a] + pbs);
      h = fmaxf(h, 0.f);
      acc16[a] = fmaf(h, wv.z, acc16[a]);
    }
  }

  float b2v = b2[0];
  float sv[2];
  int ois[2];
  unsigned mk = 0;
#pragma unroll
  for (int half = 0; half < 2; half++) {
#pragma unroll
    for (int a8 = 0; a8 < 8; a8++) accL[t >> 6][a8][lane] = acc16[half * 8 + a8];
    __syncthreads();
    {
      int a8 = t >> 6, nn = t & 63;
      float s = b2v;
#pragma unroll
      for (int ww = 0; ww < 8; ww++) s += accL[ww][a8][nn];
      int a = half * 8 + a8;
      int oi = b * AN_ + a * N_ + n0 + nn;
      bool m_ = mask[oi] != 0;
      sv[half] = m_ ? s : -1e8f;
      ois[half] = oi;
      mk |= (m_ ? 1u : 0u) << half;
    }
    __syncthreads();
  }

  float mx = fmaxf(sv[0], sv[1]);
#pragma unroll
  for (int o = 32; o > 0; o >>= 1) mx = fmaxf(mx, __shfl_xor(mx, o));
  if (lane == 0) redm[t >> 6] = mx;
  __syncthreads();
  mx = fmaxf(fmaxf(fmaxf(redm[0], redm[1]), fmaxf(redm[2], redm[3])),
             fmaxf(fmaxf(redm[4], redm[5]), fmaxf(redm[6], redm[7])));
  float ssum = 0.f;
#pragma unroll
  for (int iv = 0; iv < 2; iv++) {
    float pv = ((mk >> iv) & 1u) ? expf(sv[iv] - mx) : 0.f;
    lg[ois[iv]] = pv;
    ssum += pv;
  }
#pragma unroll
  for (int o = 32; o > 0; o >>= 1) ssum += __shfl_xor(ssum, o);
  if (lane == 0) reds[t >> 6] = ssum;
  __syncthreads();
  if (t == 0) {
    float S = ((reds[0] + reds[1]) + (reds[2] + reds[3])) +
              ((reds[4] + reds[5]) + (reds[6] + reds[7]));
    Psm[b * 16 + nt] = make_float2(mx, S);
  }
}

// ---------------- sm2: combine 16 block-partials per batch, normalize ----------------
__global__ __launch_bounds__(256) void k_sm2(const float* __restrict__ lg,
                                             const float2* __restrict__ P,
                                             float* __restrict__ out) {
  __shared__ float scs[16];
  int b = blockIdx.y, x = blockIdx.x, t = threadIdx.x;
  float M = -3.0e38f;
  float2 pr[16];
#pragma unroll
  for (int k = 0; k < 16; k++) {
    pr[k] = P[b * 16 + k];
    M = fmaxf(M, pr[k].x);
  }
  float S = 0.f;
#pragma unroll
  for (int k = 0; k < 16; k++) S += pr[k].y * expf(pr[k].x - M);
  float inv = 1.0f / S;
  if (t < 16) scs[t] = expf(pr[t].x - M) * inv;
  __syncthreads();
  const float* lb = lg + b * AN_ + x * 2048;
  float* ob = out + b * AN_ + x * 2048;
#pragma unroll
  for (int k = 0; k < 8; k++) {
    int i = t + 256 * k;
    int n = (x * 2048 + i) & 1023;
    ob[i] = lb[i] * scs[n >> 6];
  }
}

extern "C" void kernel_launch(void* const* d_in, const int* in_sizes, int n_in,
                              void* d_out, int out_size, void* d_ws, size_t ws_size,
                              hipStream_t stream) {
  const float* gn = (const float*)d_in[0];
  const int* el = (const int*)d_in[1];
  const int* loc = (const int*)d_in[2];
  const int* mask = (const int*)d_in[3];
  const float* dist = (const float*)d_in[4];
  const float* c0W = (const float*)d_in[5];
  const float* c0b = (const float*)d_in[6];
  const float* c0g = (const float*)d_in[7];
  const float* c0be = (const float*)d_in[8];
  const float* c1W = (const float*)d_in[9];
  const float* c1b = (const float*)d_in[10];
  const float* c1g = (const float*)d_in[11];
  const float* c1be = (const float*)d_in[12];
  const float* c2W = (const float*)d_in[13];
  const float* c2b = (const float*)d_in[14];
  const float* c2g = (const float*)d_in[15];
  const float* c2be = (const float*)d_in[16];
  const float* eW = (const float*)d_in[17];
  const float* eb = (const float*)d_in[18];
  const float* W1 = (const float*)d_in[19];
  const float* b1 = (const float*)d_in[20];
  const float* bng = (const float*)d_in[21];
  const float* bnb = (const float*)d_in[22];
  const float* W2 = (const float*)d_in[23];
  const float* b2 = (const float*)d_in[24];
  float* out = (float*)d_out;

  char* p = (char*)d_ws;
  auto alloc = [&](size_t bytes) {
    char* r = p;
    p += (bytes + 255) & ~(size_t)255;
    return r;
  };
  int* counts = (int*)alloc((size_t)NODES * 4);
  int* rowptr = (int*)alloc((size_t)NODES * 4);
  int* ssrc = (int*)alloc((size_t)NEDGE * 4);
  float* xc = (float*)alloc((size_t)NODES * MID_ * 4);
  float* pBT = (float*)alloc((size_t)NODES * MID_ * 4);
  float* pA = (float*)alloc((size_t)512 * MID_ * 4);
  float* cu = (float*)alloc(256 * 4);
  float* base = (float*)alloc(256 * 4);
  float* d1row = (float*)alloc((size_t)N_ * 4);
  float* c2row = (float*)alloc((size_t)N_ * 4);
  float* e1 = (float*)alloc((size_t)B_ * N_ * 4);
  float* vaT = (float*)alloc((size_t)B_ * MID_ * 16 * 4);
  float* wpack4 = (float*)alloc((size_t)MID_ * 4 * 4);
  float* lg = (float*)alloc((size_t)ROWS * 4);
  float2* Psm = (float2*)alloc((size_t)B_ * 16 * 8);
  __bf16* W1BTh = (__bf16*)alloc((size_t)MID_ * 224 * 2);
  __bf16* W1BTl = (__bf16*)alloc((size_t)MID_ * 224 * 2);
  float* SB1 = (float*)alloc((size_t)1024 * MID_ * 4);
  float* SB2 = (float*)alloc((size_t)1024 * MID_ * 4);
  float* SB3 = (float*)alloc((size_t)1024 * MID_ * 4);
  __bf16* WTh = (__bf16*)alloc((size_t)3 * 4096 * 2);
  __bf16* WTl = (__bf16*)alloc((size_t)3 * 4096 * 2);

  k_front<<<532, 256, 0, stream>>>(el, dist, loc, W1, eW, eb, b1, c0W, c1W, c2W,
                                   rowptr, counts, ssrc, d1row, c2row, e1, cu, base,
                                   W1BTh, W1BTl, WTh, WTl);

  k_layer<16, true><<<512, 256, 0, stream>>>(gn, FIN_, 0, xc, 16, rowptr, counts, ssrc,
                                             WTh, WTl, c0b, c0g, c0be);
  k_layer<64, false><<<512, 256, 0, stream>>>(xc, MID_, 16, xc, 80, rowptr, counts, ssrc,
                                              WTh + 4096, WTl + 4096, c1b, c1g, c1be);
  k_layer<64, false><<<512, 256, 0, stream>>>(xc, MID_, 80, xc, 144, rowptr, counts, ssrc,
                                              WTh + 8192, WTl + 8192, c2b, c2g, c2be);

  k_p1<<<1536, 256, 0, stream>>>(xc, W1, W1BTh, W1BTl, e1, loc, pBT, pA, SB1, SB2, SB3);
  k_fin<<<208, 256, 0, stream>>>(SB1, SB2, SB3, pA, cu, base, d1row, c2row, loc, bng, bnb, W2, vaT, wpack4);

  k_logits<<<dim3(16, 32), 512, 0, stream>>>(pBT, vaT, wpack4, dist, loc, mask, b2, lg, Psm);
  k_sm2<<<dim3(8, 32), 256, 0, stream>>>(lg, Psm, out);
}

// Round 8
// 248.049 us; speedup vs baseline: 1.0066x; 1.0066x over previous
//
#include <hip/hip_runtime.h>
#include <cstddef>

#define B_    32
#define N_    1024
#define E_    4096
#define A_    16
#define FIN_  16
#define H_    64
#define MID_  208
#define NODES (B_ * N_)      // 32768
#define NEDGE (B_ * E_)      // 131072
#define ROWS  (B_ * A_ * N_) // 524288
#define AN_   (A_ * N_)      // 16384

__device__ __forceinline__ float readlane_f(float v, int l) {
  return __uint_as_float(__builtin_amdgcn_readlane(__float_as_uint(v), l));
}

typedef __attribute__((ext_vector_type(8))) __bf16 bf16x8;
typedef __attribute__((ext_vector_type(4))) float f32x4;

__device__ __forceinline__ f32x4 mfma16(bf16x8 a, bf16x8 b, f32x4 c) {
  return __builtin_amdgcn_mfma_f32_16x16x32_bf16(a, b, c, 0, 0, 0);
}

// split 8 consecutive fp32 into bf16 hi + lo fragments (error ~2^-18 rel)
__device__ __forceinline__ void cvt8(const float* __restrict__ p, bf16x8& hi, bf16x8& lo) {
  float4 v0 = *(const float4*)p;
  float4 v1 = *(const float4*)(p + 4);
  float vv[8] = {v0.x, v0.y, v0.z, v0.w, v1.x, v1.y, v1.z, v1.w};
#pragma unroll
  for (int i = 0; i < 8; i++) {
    __bf16 h = (__bf16)vv[i];
    hi[i] = h;
    lo[i] = (__bf16)(vv[i] - (float)h);
  }
}

// ---------------- front: per-graph CSR in-block (LDS-staged ssrc) + d1 + csum + cu + W1B^T->bf16 ----------------
__global__ __launch_bounds__(256) void k_front(const int* __restrict__ el,
                                               const float* __restrict__ dist,
                                               const int* __restrict__ loc,
                                               const float* __restrict__ W1,
                                               const float* __restrict__ eW,
                                               const float* __restrict__ eb,
                                               const float* __restrict__ b1,
                                               int* __restrict__ rowptr,
                                               int* __restrict__ counts,
                                               int* __restrict__ ssrc,
                                               float* __restrict__ d1row,
                                               float* __restrict__ c2row,
                                               float* __restrict__ e1,
                                               float* __restrict__ cu,
                                               float* __restrict__ base,
                                               __bf16* __restrict__ W1BTh,
                                               __bf16* __restrict__ W1BTl) {
  __shared__ int cnt[1024];
  __shared__ int cur[1024];
  __shared__ int part[256];
  __shared__ int ssrcS[4096];
  __shared__ int loc_s[16];
  int blk = blockIdx.x, t = threadIdx.x;
  if (blk < 32) {
    int b = blk;
    for (int i = t; i < 1024; i += 256) cnt[i] = 0;
    __syncthreads();
    const int* srcp = el + b * (2 * E_);
    const int* dstp = srcp + E_;
    for (int i = t; i < E_; i += 256) atomicAdd(&cnt[dstp[i]], 1);
    __syncthreads();
    int4 c4 = *(const int4*)&cnt[t * 4];
    int s = c4.x + c4.y + c4.z + c4.w;
    part[t] = s;
    __syncthreads();
    for (int off = 1; off < 256; off <<= 1) {
      int v = (t >= off) ? part[t - off] : 0;
      __syncthreads();
      part[t] += v;
      __syncthreads();
    }
    int prev = (t == 0) ? 0 : part[t - 1];
    int p0 = prev, p1 = p0 + c4.x, p2 = p1 + c4.y, p3 = p2 + c4.z;
    *(int4*)&rowptr[b * 1024 + t * 4] = make_int4(p0 + b * E_, p1 + b * E_, p2 + b * E_, p3 + b * E_);
    *(int4*)&counts[b * 1024 + t * 4] = c4;
    cur[t * 4 + 0] = p0;
    cur[t * 4 + 1] = p1;
    cur[t * 4 + 2] = p2;
    cur[t * 4 + 3] = p3;
    __syncthreads();
    for (int i = t; i < E_; i += 256) {
      int dl = dstp[i];
      int sl = srcp[i];
      int pos = atomicAdd(&cur[dl], 1);
      ssrcS[pos] = b * N_ + sl;
    }
    __syncthreads();
    for (int i = t; i < E_; i += 256) ssrc[b * E_ + i] = ssrcS[i];
  } else if (blk < 288) {
    int lane = t & 63, w = t >> 6;
    int r = (blk - 32) * 4 + w;
    const float* dr = dist + (size_t)r * N_;
    float s = 0.f, c2 = 0.f;
#pragma unroll
    for (int k = 0; k < 16; k++) {
      float v = dr[lane + 64 * k];
      s += v;
      c2 = fmaf(v, v, c2);
    }
#pragma unroll
    for (int o = 32; o > 0; o >>= 1) { s += __shfl_xor(s, o); c2 += __shfl_xor(c2, o); }
    if (lane == 0) { d1row[r] = s; c2row[r] = c2; }
  } else if (blk < 320) {
    int b = blk - 288;
    if (t < 16) loc_s[t] = loc[b * 16 + t];
    __syncthreads();
    float e4[4] = {0.f, 0.f, 0.f, 0.f};
    for (int a = 0; a < 16; a++) {
      const float* dr = dist + (size_t)loc_s[a] * N_;
#pragma unroll
      for (int k = 0; k < 4; k++) e4[k] += dr[t + 256 * k];
    }
#pragma unroll
    for (int k = 0; k < 4; k++) e1[b * N_ + t + 256 * k] = e4[k];
  } else if (blk == 320) {
    int j = t;
    if (j < MID_) {
      float c = 0.f, bs = 0.f;
      for (int k = 0; k < H_; k++) {
        float w = W1[(2 * MID_ + k) * MID_ + j];
        c = fmaf(eW[k], w, c);
        bs = fmaf(eb[k], w, bs);
      }
      cu[j] = c;
      base[j] = bs + b1[j];
    }
  } else {
    // W1B^T conversion to bf16 hi/lo, row j = blk-321, k padded to 224 with zeros
    int jr = blk - 321;
    if (t < 224) {
      float v = (t < MID_) ? W1[(size_t)(MID_ + t) * MID_ + jr] : 0.f;
      __bf16 h = (__bf16)v;
      W1BTh[jr * 224 + t] = h;
      W1BTl[jr * 224 + t] = (__bf16)(v - (float)h);
    }
  }
}

// ---------------- GIN layer: XCD-swizzled blocks; wave per 8 nodes ----------------
template <int FINT, bool COPYIN>
__global__ __launch_bounds__(256) void k_layer(const float* __restrict__ xin, int xstride, int in_off,
                                               float* __restrict__ xc, int out_off,
                                               const int* __restrict__ rowptr,
                                               const int* __restrict__ counts,
                                               const int* __restrict__ ssrc,
                                               const float* __restrict__ W,
                                               const float* __restrict__ bias,
                                               const float* __restrict__ g,
                                               const float* __restrict__ beta) {
  int t = threadIdx.x, lane = t & 63, w = t >> 6;
  float Wcol[FINT];
#pragma unroll
  for (int f = 0; f < FINT; f++) Wcol[f] = W[f * 64 + lane];
  float bv = bias[lane], gv = g[lane], bev = beta[lane];
  constexpr int CH = 64 / FINT;
  int f = lane & (FINT - 1);
  int ch = (FINT == 64) ? 0 : (lane >> 4);
  int blk = blockIdx.x;
  int xcd = blk & 7, kk = blk >> 3;
  int graph = xcd * 4 + (kk >> 5);
  int nblk = kk & 31;
  int nbase = graph * N_ + nblk * 32 + w * 8;

  float agg[8];
#pragma unroll
  for (int nn = 0; nn < 8; nn++) {
    int node = nbase + nn;
    int r0 = rowptr[node];
    int deg = counts[node];
    float a0 = 0.f, a1 = 0.f, a2 = 0.f, a3 = 0.f;
    int e = ch;
    for (; e + 3 * CH < deg; e += 4 * CH) {
      int s0 = ssrc[r0 + e];
      int s1 = ssrc[r0 + e + CH];
      int s2 = ssrc[r0 + e + 2 * CH];
      int s3 = ssrc[r0 + e + 3 * CH];
      a0 += xin[(size_t)s0 * xstride + in_off + f];
      a1 += xin[(size_t)s1 * xstride + in_off + f];
      a2 += xin[(size_t)s2 * xstride + in_off + f];
      a3 += xin[(size_t)s3 * xstride + in_off + f];
    }
    for (; e < deg; e += CH) {
      int s = ssrc[r0 + e];
      a0 += xin[(size_t)s * xstride + in_off + f];
    }
    agg[nn] = (a0 + a1) + (a2 + a3);
  }

#pragma unroll
  for (int nn = 0; nn < 8; nn++) {
    int node = nbase + nn;
    float aggf = agg[nn];
    float y0 = bv, y1 = 0.f, y2 = 0.f, y3 = 0.f;
#pragma unroll
    for (int l = 0; l < 64; l += 4) {
      y0 = fmaf(readlane_f(aggf, l + 0), Wcol[(l + 0) & (FINT - 1)], y0);
      y1 = fmaf(readlane_f(aggf, l + 1), Wcol[(l + 1) & (FINT - 1)], y1);
      y2 = fmaf(readlane_f(aggf, l + 2), Wcol[(l + 2) & (FINT - 1)], y2);
      y3 = fmaf(readlane_f(aggf, l + 3), Wcol[(l + 3) & (FINT - 1)], y3);
    }
    float y = (y0 + y1) + (y2 + y3);
    float m = y;
#pragma unroll
    for (int o = 32; o > 0; o >>= 1) m += __shfl_xor(m, o);
    m *= (1.f / 64.f);
    float d = y - m;
    float vv = d * d;
#pragma unroll
    for (int o = 32; o > 0; o >>= 1) vv += __shfl_xor(vv, o);
    vv *= (1.f / 64.f);
    float outv = fmaxf(d * rsqrtf(vv + 1e-5f) * gv + bev, 0.f);
    xc[(size_t)node * MID_ + out_off + lane] = outv;
    if (COPYIN) {
      if (lane < FIN_) xc[(size_t)node * MID_ + lane] = xin[(size_t)node * FIN_ + lane];
    }
  }
}

// ---------------- p1: blk<1024: MFMA GEMM pBT (bf16 hi/lo split) + in-register column stats; blk>=1024: pA ----------------
__global__ __launch_bounds__(256) void k_p1(const float* __restrict__ xc,
                                            const float* __restrict__ W1,
                                            const __bf16* __restrict__ W1BTh,
                                            const __bf16* __restrict__ W1BTl,
                                            const float* __restrict__ e1,
                                            const int* __restrict__ loc,
                                            float* __restrict__ pBT,
                                            float* __restrict__ pA,
                                            float* __restrict__ SB1,
                                            float* __restrict__ SB2,
                                            float* __restrict__ SB3) {
  __shared__ float xr[MID_];
  int t = threadIdx.x, lane = t & 63;
  int w = t >> 6;
  int blk = blockIdx.x;
  if (blk < 1024) {
    int nb = blk * 32;
    int q = lane >> 4, li = lane & 15;
    int jt0 = (w == 0) ? 0 : (w == 1) ? 4 : (w == 2) ? 7 : 10;
    int njt = (w == 0) ? 4 : 3;
    f32x4 zero4 = {0.f, 0.f, 0.f, 0.f};
    f32x4 acc0[4], acc1[4];
#pragma unroll
    for (int i = 0; i < 4; i++) { acc0[i] = zero4; acc1[i] = zero4; }
    const float* xr0 = xc + (size_t)(nb + li) * MID_;
    const float* xr1 = xc + (size_t)(nb + 16 + li) * MID_;
    for (int kc = 0; kc < 7; kc++) {
      int k0 = kc * 32 + q * 8;
      bf16x8 b0h, b0l, b1h, b1l;
      if (k0 < MID_) {
        cvt8(xr0 + k0, b0h, b0l);
        cvt8(xr1 + k0, b1h, b1l);
      } else {
#pragma unroll
        for (int i = 0; i < 8; i++) {
          b0h[i] = (__bf16)0.f; b0l[i] = (__bf16)0.f;
          b1h[i] = (__bf16)0.f; b1l[i] = (__bf16)0.f;
        }
      }
#pragma unroll
      for (int jj = 0; jj < 4; jj++) {
        if (jj < njt) {
          int jt = jt0 + jj;
          bf16x8 ah = *(const bf16x8*)(W1BTh + (size_t)(jt * 16 + li) * 224 + k0);
          bf16x8 al = *(const bf16x8*)(W1BTl + (size_t)(jt * 16 + li) * 224 + k0);
          acc0[jj] = mfma16(ah, b0h, acc0[jj]);
          acc0[jj] = mfma16(ah, b0l, acc0[jj]);
          acc0[jj] = mfma16(al, b0h, acc0[jj]);
          acc1[jj] = mfma16(ah, b1h, acc1[jj]);
          acc1[jj] = mfma16(ah, b1l, acc1[jj]);
          acc1[jj] = mfma16(al, b1h, acc1[jj]);
        }
      }
    }
    float ev0 = e1[nb + li];
    float ev1 = e1[nb + 16 + li];
#pragma unroll
    for (int jj = 0; jj < 4; jj++) {
      if (jj < njt) {
        int jt = jt0 + jj;
#pragma unroll
        for (int r = 0; r < 4; r++) {
          int j = jt * 16 + q * 4 + r;
          float* pb = pBT + (size_t)j * NODES + nb + li;
          pb[0] = acc0[jj][r];
          pb[16] = acc1[jj][r];
        }
        float s1v[4], s2v[4], s3v[4];
#pragma unroll
        for (int r = 0; r < 4; r++) {
          float a0 = acc0[jj][r], a1 = acc1[jj][r];
          s1v[r] = a0 + a1;
          s2v[r] = fmaf(a0, a0, a1 * a1);
          s3v[r] = fmaf(a0, ev0, a1 * ev1);
        }
#pragma unroll
        for (int o = 8; o > 0; o >>= 1) {
#pragma unroll
          for (int r = 0; r < 4; r++) {
            s1v[r] += __shfl_xor(s1v[r], o);
            s2v[r] += __shfl_xor(s2v[r], o);
            s3v[r] += __shfl_xor(s3v[r], o);
          }
        }
        if (li < 4) {
          float g1 = (li == 0) ? s1v[0] : (li == 1) ? s1v[1] : (li == 2) ? s1v[2] : s1v[3];
          float g2 = (li == 0) ? s2v[0] : (li == 1) ? s2v[1] : (li == 2) ? s2v[2] : s2v[3];
          float g3 = (li == 0) ? s3v[0] : (li == 1) ? s3v[1] : (li == 2) ? s3v[2] : s3v[3];
          int j = jt * 16 + q * 4 + li;
          SB1[(size_t)blk * MID_ + j] = g1;
          SB2[(size_t)blk * MID_ + j] = g2;
          SB3[(size_t)blk * MID_ + j] = g3;
        }
      }
    }
  } else {
    int ab = blk - 1024;           // b*16 + a
    int b = ab >> 4;
    int node = b * N_ + loc[ab];
    for (int i = t; i < MID_; i += 256) xr[i] = xc[(size_t)node * MID_ + i];
    __syncthreads();
    if (t < MID_) {
      float acc = 0.f;
      for (int i = 0; i < MID_; i++) acc = fmaf(xr[i], W1[i * MID_ + t], acc);
      pA[ab * MID_ + t] = acc;
    }
  }
}

// ---------------- fin: one block per feature j — stats from SB partials + BN finalize + vaT + wpack ----------------
__global__ __launch_bounds__(256) void k_fin(const float* __restrict__ SB1,
                                             const float* __restrict__ SB2,
                                             const float* __restrict__ SB3,
                                             const float* __restrict__ pA,
                                             const float* __restrict__ cu,
                                             const float* __restrict__ base,
                                             const float* __restrict__ d1row,
                                             const float* __restrict__ c2row,
                                             const int* __restrict__ loc,
                                             const float* __restrict__ bng,
                                             const float* __restrict__ bnb,
                                             const float* __restrict__ W2,
                                             float* __restrict__ vaT,
                                             float* __restrict__ wpack4) {
  __shared__ float utmp[1536 + 192];
  __shared__ float redm[4];
  __shared__ float reds[4];
  __shared__ float bcast[2];
  int t = threadIdx.x, lane = t & 63, w = t >> 6;
  int j = blockIdx.x;
  float cuj = cu[j], bj = base[j];
  float q1 = 0.f, q2 = 0.f, q3 = 0.f;
#pragma unroll
  for (int c = t * 4; c < t * 4 + 4; c++) {
    q1 += SB1[(size_t)c * MID_ + j];
    q2 += SB2[(size_t)c * MID_ + j];
    q3 += SB3[(size_t)c * MID_ + j];
  }
  float t1 = 0.f, t2 = 0.f, t3 = 0.f;
#pragma unroll
  for (int r = t * 2; r < t * 2 + 2; r++) {
    float pa = pA[r * MID_ + j] + bj;
    t1 += pa;
    t2 = fmaf(pa, pa, t2);
    t3 = fmaf(pa, d1row[loc[r]], t3);
  }
  utmp[0 * 256 + t] = q1;
  utmp[1 * 256 + t] = q2;
  utmp[2 * 256 + t] = q3;
  utmp[3 * 256 + t] = t1;
  utmp[4 * 256 + t] = t2;
  utmp[5 * 256 + t] = t3;
  float p1 = 0.f, p2 = 0.f;
#pragma unroll
  for (int r = t * 2; r < t * 2 + 2; r++) {
    int l = loc[r];
    p1 += d1row[l];
    p2 += c2row[l];
  }
#pragma unroll
  for (int o = 32; o > 0; o >>= 1) { p1 += __shfl_xor(p1, o); p2 += __shfl_xor(p2, o); }
  if (lane == 0) { redm[w] = p1; reds[w] = p2; }
  __syncthreads();
  if (t < 192) {
    int s = t >> 5, b32 = t & 31;
    float ssum = 0.f;
#pragma unroll
    for (int i = 0; i < 8; i++) ssum += utmp[s * 256 + b32 * 8 + i];
    utmp[1536 + s * 32 + b32] = ssum;
  }
  __syncthreads();
  if (t == 0) {
    float Sc1 = (redm[0] + redm[1]) + (redm[2] + redm[3]);
    float Sc2 = (reds[0] + reds[1]) + (reds[2] + reds[3]);
    double T1 = 0, T2 = 0, T3 = 0, cross = 0, sp1 = 0, sp2 = 0, spe = 0;
    for (int b = 0; b < 32; b++) {
      float sq1 = utmp[1536 + 0 * 32 + b];
      float sq2 = utmp[1536 + 1 * 32 + b];
      float sq3 = utmp[1536 + 2 * 32 + b];
      float pt1 = utmp[1536 + 3 * 32 + b];
      float pt2 = utmp[1536 + 4 * 32 + b];
      float pt3 = utmp[1536 + 5 * 32 + b];
      T1 += pt1; T2 += pt2; T3 += pt3;
      cross += (double)pt1 * sq1;
      sp1 += sq1; sp2 += sq2; spe += sq3;
    }
    double s1 = 1024.0 * T1 + 16.0 * sp1 + (double)cuj * Sc1;
    double s2 = 1024.0 * T2 + 16.0 * sp2 + (double)cuj * cuj * Sc2 +
                2.0 * (cross + (double)cuj * (T3 + spe));
    double mu = s1 * (1.0 / (double)ROWS);
    double var = s2 * (1.0 / (double)ROWS) - mu * mu;
    float sc = (float)(1.0 / sqrt(var + 1e-5)) * bng[j];
    float sh = bnb[j] - (float)mu * sc;
    bcast[0] = sc;
    bcast[1] = sh;
    wpack4[4 * j + 0] = sc;
    wpack4[4 * j + 1] = cuj * sc;
    wpack4[4 * j + 2] = W2[j];
    wpack4[4 * j + 3] = 0.f;
  }
  __syncthreads();
  float sc = bcast[0], sh = bcast[1];
#pragma unroll
  for (int r = t * 2; r < t * 2 + 2; r++) {
    int b = r >> 4, a = r & 15;
    float pa = pA[r * MID_ + j] + bj;
    vaT[((size_t)b * MID_ + j) * 16 + a] = pa * sc + sh;
  }
}

// ---------------- logits: 512 threads (8 waves x 26 j's) for 2x occupancy; + softmax partials ----------------
__global__ __launch_bounds__(512) void k_logits(const float* __restrict__ pBT,
                                                const float* __restrict__ vaT,
                                                const float* __restrict__ wpack4,
                                                const float* __restrict__ dist,
                                                const int* __restrict__ loc,
                                                const int* __restrict__ mask,
                                                const float* __restrict__ b2,
                                                float* __restrict__ lg,
                                                float2* __restrict__ Psm) {
  __shared__ float vaS[MID_ * 16];
  __shared__ float accL[8][8][64];
  __shared__ int loc_s[16];
  __shared__ float redm[8];
  __shared__ float reds[8];
  int t = threadIdx.x, lane = t & 63;
  int w = __builtin_amdgcn_readfirstlane(t >> 6);   // 0..7
  int b = blockIdx.y, nt = blockIdx.x;
  int n0 = nt * 64;
  if (t < 16) loc_s[t] = loc[b * 16 + t];
  for (int i = t; i < MID_ * 16; i += 512) vaS[i] = vaT[(size_t)b * MID_ * 16 + i];
  __syncthreads();
  float c[16];
#pragma unroll
  for (int a = 0; a < 16; a++) c[a] = dist[(size_t)loc_s[a] * N_ + n0 + lane];
  float acc16[16];
#pragma unroll
  for (int a = 0; a < 16; a++) acc16[a] = 0.f;
  const float4* wp = (const float4*)wpack4;
  int ng = b * N_ + n0 + lane;
  int jb = w * 26;
#pragma unroll 2
  for (int jj = 0; jj < 26; jj++) {
    int j = jb + jj;
    float pbv = pBT[(size_t)j * NODES + ng];
    float4 wv = wp[j];
    float pbs = pbv * wv.x;
    const float* va = &vaS[j * 16];
#pragma unroll
    for (int a = 0; a < 16; a++) {
      float h = fmaf(c[a], wv.y, va[a] + pbs);
      h = fmaxf(h, 0.f);
      acc16[a] = fmaf(h, wv.z, acc16[a]);
    }
  }

  float b2v = b2[0];
  float sv[2];
  int ois[2];
  unsigned mk = 0;
#pragma unroll
  for (int half = 0; half < 2; half++) {
#pragma unroll
    for (int a8 = 0; a8 < 8; a8++) accL[t >> 6][a8][lane] = acc16[half * 8 + a8];
    __syncthreads();
    {
      int a8 = t >> 6, nn = t & 63;
      float s = b2v;
#pragma unroll
      for (int ww = 0; ww < 8; ww++) s += accL[ww][a8][nn];
      int a = half * 8 + a8;
      int oi = b * AN_ + a * N_ + n0 + nn;
      bool m_ = mask[oi] != 0;
      sv[half] = m_ ? s : -1e8f;
      ois[half] = oi;
      mk |= (m_ ? 1u : 0u) << half;
    }
    __syncthreads();
  }

  float mx = fmaxf(sv[0], sv[1]);
#pragma unroll
  for (int o = 32; o > 0; o >>= 1) mx = fmaxf(mx, __shfl_xor(mx, o));
  if (lane == 0) redm[t >> 6] = mx;
  __syncthreads();
  mx = fmaxf(fmaxf(fmaxf(redm[0], redm[1]), fmaxf(redm[2], redm[3])),
             fmaxf(fmaxf(redm[4], redm[5]), fmaxf(redm[6], redm[7])));
  float ssum = 0.f;
#pragma unroll
  for (int iv = 0; iv < 2; iv++) {
    float pv = ((mk >> iv) & 1u) ? expf(sv[iv] - mx) : 0.f;
    lg[ois[iv]] = pv;
    ssum += pv;
  }
#pragma unroll
  for (int o = 32; o > 0; o >>= 1) ssum += __shfl_xor(ssum, o);
  if (lane == 0) reds[t >> 6] = ssum;
  __syncthreads();
  if (t == 0) {
    float S = ((reds[0] + reds[1]) + (reds[2] + reds[3])) +
              ((reds[4] + reds[5]) + (reds[6] + reds[7]));
    Psm[b * 16 + nt] = make_float2(mx, S);
  }
}

// ---------------- sm2: combine 16 block-partials per batch, normalize ----------------
__global__ __launch_bounds__(256) void k_sm2(const float* __restrict__ lg,
                                             const float2* __restrict__ P,
                                             float* __restrict__ out) {
  __shared__ float scs[16];
  int b = blockIdx.y, x = blockIdx.x, t = threadIdx.x;
  float M = -3.0e38f;
  float2 pr[16];
#pragma unroll
  for (int k = 0; k < 16; k++) {
    pr[k] = P[b * 16 + k];
    M = fmaxf(M, pr[k].x);
  }
  float S = 0.f;
#pragma unroll
  for (int k = 0; k < 16; k++) S += pr[k].y * expf(pr[k].x - M);
  float inv = 1.0f / S;
  if (t < 16) scs[t] = expf(pr[t].x - M) * inv;
  __syncthreads();
  const float* lb = lg + b * AN_ + x * 2048;
  float* ob = out + b * AN_ + x * 2048;
#pragma unroll
  for (int k = 0; k < 8; k++) {
    int i = t + 256 * k;
    int n = (x * 2048 + i) & 1023;
    ob[i] = lb[i] * scs[n >> 6];
  }
}

extern "C" void kernel_launch(void* const* d_in, const int* in_sizes, int n_in,
                              void* d_out, int out_size, void* d_ws, size_t ws_size,
                              hipStream_t stream) {
  const float* gn = (const float*)d_in[0];
  const int* el = (const int*)d_in[1];
  const int* loc = (const int*)d_in[2];
  const int* mask = (const int*)d_in[3];
  const float* dist = (const float*)d_in[4];
  const float* c0W = (const float*)d_in[5];
  const float* c0b = (const float*)d_in[6];
  const float* c0g = (const float*)d_in[7];
  const float* c0be = (const float*)d_in[8];
  const float* c1W = (const float*)d_in[9];
  const float* c1b = (const float*)d_in[10];
  const float* c1g = (const float*)d_in[11];
  const float* c1be = (const float*)d_in[12];
  const float* c2W = (const float*)d_in[13];
  const float* c2b = (const float*)d_in[14];
  const float* c2g = (const float*)d_in[15];
  const float* c2be = (const float*)d_in[16];
  const float* eW = (const float*)d_in[17];
  const float* eb = (const float*)d_in[18];
  const float* W1 = (const float*)d_in[19];
  const float* b1 = (const float*)d_in[20];
  const float* bng = (const float*)d_in[21];
  const float* bnb = (const float*)d_in[22];
  const float* W2 = (const float*)d_in[23];
  const float* b2 = (const float*)d_in[24];
  float* out = (float*)d_out;

  char* p = (char*)d_ws;
  auto alloc = [&](size_t bytes) {
    char* r = p;
    p += (bytes + 255) & ~(size_t)255;
    return r;
  };
  int* counts = (int*)alloc((size_t)NODES * 4);
  int* rowptr = (int*)alloc((size_t)NODES * 4);
  int* ssrc = (int*)alloc((size_t)NEDGE * 4);
  float* xc = (float*)alloc((size_t)NODES * MID_ * 4);
  float* pBT = (float*)alloc((size_t)NODES * MID_ * 4);
  float* pA = (float*)alloc((size_t)512 * MID_ * 4);
  float* cu = (float*)alloc(256 * 4);
  float* base = (float*)alloc(256 * 4);
  float* d1row = (float*)alloc((size_t)N_ * 4);
  float* c2row = (float*)alloc((size_t)N_ * 4);
  float* e1 = (float*)alloc((size_t)B_ * N_ * 4);
  float* vaT = (float*)alloc((size_t)B_ * MID_ * 16 * 4);
  float* wpack4 = (float*)alloc((size_t)MID_ * 4 * 4);
  float* lg = (float*)alloc((size_t)ROWS * 4);
  float2* Psm = (float2*)alloc((size_t)B_ * 16 * 8);
  __bf16* W1BTh = (__bf16*)alloc((size_t)MID_ * 224 * 2);
  __bf16* W1BTl = (__bf16*)alloc((size_t)MID_ * 224 * 2);
  float* SB1 = (float*)alloc((size_t)1024 * MID_ * 4);
  float* SB2 = (float*)alloc((size_t)1024 * MID_ * 4);
  float* SB3 = (float*)alloc((size_t)1024 * MID_ * 4);

  k_front<<<529, 256, 0, stream>>>(el, dist, loc, W1, eW, eb, b1,
                                   rowptr, counts, ssrc, d1row, c2row, e1, cu, base,
                                   W1BTh, W1BTl);

  k_layer<16, true><<<1024, 256, 0, stream>>>(gn, FIN_, 0, xc, 16, rowptr, counts, ssrc, c0W, c0b, c0g, c0be);
  k_layer<64, false><<<1024, 256, 0, stream>>>(xc, MID_, 16, xc, 80, rowptr, counts, ssrc, c1W, c1b, c1g, c1be);
  k_layer<64, false><<<1024, 256, 0, stream>>>(xc, MID_, 80, xc, 144, rowptr, counts, ssrc, c2W, c2b, c2g, c2be);

  k_p1<<<1536, 256, 0, stream>>>(xc, W1, W1BTh, W1BTl, e1, loc, pBT, pA, SB1, SB2, SB3);
  k_fin<<<208, 256, 0, stream>>>(SB1, SB2, SB3, pA, cu, base, d1row, c2row, loc, bng, bnb, W2, vaT, wpack4);

  k_logits<<<dim3(16, 32), 512, 0, stream>>>(pBT, vaT, wpack4, dist, loc, mask, b2, lg, Psm);
  k_sm2<<<dim3(8, 32), 256, 0, stream>>>(lg, Psm, out);
}

// Round 9
// 244.425 us; speedup vs baseline: 1.0215x; 1.0148x over previous
//
#include <hip/hip_runtime.h>
#include <cstddef>

#define B_    32
#define N_    1024
#define E_    4096
#define A_    16
#define FIN_  16
#define H_    64
#define MID_  208
#define NODES (B_ * N_)      // 32768
#define NEDGE (B_ * E_)      // 131072
#define ROWS  (B_ * A_ * N_) // 524288
#define AN_   (A_ * N_)      // 16384

__device__ __forceinline__ float readlane_f(float v, int l) {
  return __uint_as_float(__builtin_amdgcn_readlane(__float_as_uint(v), l));
}

typedef __attribute__((ext_vector_type(8))) __bf16 bf16x8;
typedef __attribute__((ext_vector_type(4))) float f32x4;

__device__ __forceinline__ f32x4 mfma16(bf16x8 a, bf16x8 b, f32x4 c) {
  return __builtin_amdgcn_mfma_f32_16x16x32_bf16(a, b, c, 0, 0, 0);
}

// split 8 consecutive fp32 into bf16 hi + lo fragments (error ~2^-18 rel)
__device__ __forceinline__ void cvt8(const float* __restrict__ p, bf16x8& hi, bf16x8& lo) {
  float4 v0 = *(const float4*)p;
  float4 v1 = *(const float4*)(p + 4);
  float vv[8] = {v0.x, v0.y, v0.z, v0.w, v1.x, v1.y, v1.z, v1.w};
#pragma unroll
  for (int i = 0; i < 8; i++) {
    __bf16 h = (__bf16)vv[i];
    hi[i] = h;
    lo[i] = (__bf16)(vv[i] - (float)h);
  }
}

// ---------------- front: per-graph CSR in-block (LDS-staged ssrc) + d1 + csum + cu + W1B^T->bf16 ----------------
__global__ __launch_bounds__(256) void k_front(const int* __restrict__ el,
                                               const float* __restrict__ dist,
                                               const int* __restrict__ loc,
                                               const float* __restrict__ W1,
                                               const float* __restrict__ eW,
                                               const float* __restrict__ eb,
                                               const float* __restrict__ b1,
                                               int* __restrict__ rowptr,
                                               int* __restrict__ counts,
                                               int* __restrict__ ssrc,
                                               float* __restrict__ d1row,
                                               float* __restrict__ c2row,
                                               float* __restrict__ e1,
                                               float* __restrict__ cu,
                                               float* __restrict__ base,
                                               __bf16* __restrict__ W1BTh,
                                               __bf16* __restrict__ W1BTl) {
  __shared__ int cnt[1024];
  __shared__ int cur[1024];
  __shared__ int part[256];
  __shared__ int ssrcS[4096];
  __shared__ int loc_s[16];
  int blk = blockIdx.x, t = threadIdx.x;
  if (blk < 32) {
    int b = blk;
    for (int i = t; i < 1024; i += 256) cnt[i] = 0;
    __syncthreads();
    const int* srcp = el + b * (2 * E_);
    const int* dstp = srcp + E_;
    for (int i = t; i < E_; i += 256) atomicAdd(&cnt[dstp[i]], 1);
    __syncthreads();
    int4 c4 = *(const int4*)&cnt[t * 4];
    int s = c4.x + c4.y + c4.z + c4.w;
    part[t] = s;
    __syncthreads();
    for (int off = 1; off < 256; off <<= 1) {
      int v = (t >= off) ? part[t - off] : 0;
      __syncthreads();
      part[t] += v;
      __syncthreads();
    }
    int prev = (t == 0) ? 0 : part[t - 1];
    int p0 = prev, p1 = p0 + c4.x, p2 = p1 + c4.y, p3 = p2 + c4.z;
    *(int4*)&rowptr[b * 1024 + t * 4] = make_int4(p0 + b * E_, p1 + b * E_, p2 + b * E_, p3 + b * E_);
    *(int4*)&counts[b * 1024 + t * 4] = c4;
    cur[t * 4 + 0] = p0;
    cur[t * 4 + 1] = p1;
    cur[t * 4 + 2] = p2;
    cur[t * 4 + 3] = p3;
    __syncthreads();
    for (int i = t; i < E_; i += 256) {
      int dl = dstp[i];
      int sl = srcp[i];
      int pos = atomicAdd(&cur[dl], 1);
      ssrcS[pos] = b * N_ + sl;
    }
    __syncthreads();
    for (int i = t; i < E_; i += 256) ssrc[b * E_ + i] = ssrcS[i];
  } else if (blk < 288) {
    int lane = t & 63, w = t >> 6;
    int r = (blk - 32) * 4 + w;
    const float* dr = dist + (size_t)r * N_;
    float s = 0.f, c2 = 0.f;
#pragma unroll
    for (int k = 0; k < 16; k++) {
      float v = dr[lane + 64 * k];
      s += v;
      c2 = fmaf(v, v, c2);
    }
#pragma unroll
    for (int o = 32; o > 0; o >>= 1) { s += __shfl_xor(s, o); c2 += __shfl_xor(c2, o); }
    if (lane == 0) { d1row[r] = s; c2row[r] = c2; }
  } else if (blk < 320) {
    int b = blk - 288;
    if (t < 16) loc_s[t] = loc[b * 16 + t];
    __syncthreads();
    float e4[4] = {0.f, 0.f, 0.f, 0.f};
    for (int a = 0; a < 16; a++) {
      const float* dr = dist + (size_t)loc_s[a] * N_;
#pragma unroll
      for (int k = 0; k < 4; k++) e4[k] += dr[t + 256 * k];
    }
#pragma unroll
    for (int k = 0; k < 4; k++) e1[b * N_ + t + 256 * k] = e4[k];
  } else if (blk == 320) {
    int j = t;
    if (j < MID_) {
      float c = 0.f, bs = 0.f;
      for (int k = 0; k < H_; k++) {
        float w = W1[(2 * MID_ + k) * MID_ + j];
        c = fmaf(eW[k], w, c);
        bs = fmaf(eb[k], w, bs);
      }
      cu[j] = c;
      base[j] = bs + b1[j];
    }
  } else {
    // W1B^T conversion to bf16 hi/lo, row j = blk-321, k padded to 224 with zeros
    int jr = blk - 321;
    if (t < 224) {
      float v = (t < MID_) ? W1[(size_t)(MID_ + t) * MID_ + jr] : 0.f;
      __bf16 h = (__bf16)v;
      W1BTh[jr * 224 + t] = h;
      W1BTl[jr * 224 + t] = (__bf16)(v - (float)h);
    }
  }
}

// ---------------- GIN layer: XCD-swizzled blocks; wave per 8 nodes ----------------
template <int FINT, bool COPYIN>
__global__ __launch_bounds__(256) void k_layer(const float* __restrict__ xin, int xstride, int in_off,
                                               float* __restrict__ xc, int out_off,
                                               const int* __restrict__ rowptr,
                                               const int* __restrict__ counts,
                                               const int* __restrict__ ssrc,
                                               const float* __restrict__ W,
                                               const float* __restrict__ bias,
                                               const float* __restrict__ g,
                                               const float* __restrict__ beta) {
  int t = threadIdx.x, lane = t & 63, w = t >> 6;
  float Wcol[FINT];
#pragma unroll
  for (int f = 0; f < FINT; f++) Wcol[f] = W[f * 64 + lane];
  float bv = bias[lane], gv = g[lane], bev = beta[lane];
  constexpr int CH = 64 / FINT;
  int f = lane & (FINT - 1);
  int ch = (FINT == 64) ? 0 : (lane >> 4);
  int blk = blockIdx.x;
  int xcd = blk & 7, kk = blk >> 3;
  int graph = xcd * 4 + (kk >> 5);
  int nblk = kk & 31;
  int nbase = graph * N_ + nblk * 32 + w * 8;

  float agg[8];
#pragma unroll
  for (int nn = 0; nn < 8; nn++) {
    int node = nbase + nn;
    int r0 = rowptr[node];
    int deg = counts[node];
    float a0 = 0.f, a1 = 0.f, a2 = 0.f, a3 = 0.f;
    int e = ch;
    for (; e + 3 * CH < deg; e += 4 * CH) {
      int s0 = ssrc[r0 + e];
      int s1 = ssrc[r0 + e + CH];
      int s2 = ssrc[r0 + e + 2 * CH];
      int s3 = ssrc[r0 + e + 3 * CH];
      a0 += xin[(size_t)s0 * xstride + in_off + f];
      a1 += xin[(size_t)s1 * xstride + in_off + f];
      a2 += xin[(size_t)s2 * xstride + in_off + f];
      a3 += xin[(size_t)s3 * xstride + in_off + f];
    }
    for (; e < deg; e += CH) {
      int s = ssrc[r0 + e];
      a0 += xin[(size_t)s * xstride + in_off + f];
    }
    agg[nn] = (a0 + a1) + (a2 + a3);
  }

#pragma unroll
  for (int nn = 0; nn < 8; nn++) {
    int node = nbase + nn;
    float aggf = agg[nn];
    float y0 = bv, y1 = 0.f, y2 = 0.f, y3 = 0.f;
#pragma unroll
    for (int l = 0; l < 64; l += 4) {
      y0 = fmaf(readlane_f(aggf, l + 0), Wcol[(l + 0) & (FINT - 1)], y0);
      y1 = fmaf(readlane_f(aggf, l + 1), Wcol[(l + 1) & (FINT - 1)], y1);
      y2 = fmaf(readlane_f(aggf, l + 2), Wcol[(l + 2) & (FINT - 1)], y2);
      y3 = fmaf(readlane_f(aggf, l + 3), Wcol[(l + 3) & (FINT - 1)], y3);
    }
    float y = (y0 + y1) + (y2 + y3);
    float m = y;
#pragma unroll
    for (int o = 32; o > 0; o >>= 1) m += __shfl_xor(m, o);
    m *= (1.f / 64.f);
    float d = y - m;
    float vv = d * d;
#pragma unroll
    for (int o = 32; o > 0; o >>= 1) vv += __shfl_xor(vv, o);
    vv *= (1.f / 64.f);
    float outv = fmaxf(d * rsqrtf(vv + 1e-5f) * gv + bev, 0.f);
    xc[(size_t)node * MID_ + out_off + lane] = outv;
    if (COPYIN) {
      if (lane < FIN_) xc[(size_t)node * MID_ + lane] = xin[(size_t)node * FIN_ + lane];
    }
  }
}

// ---------------- p1: blk<1024: MFMA GEMM pBT (bf16 hi/lo split) + in-register column stats; blk>=1024: pA ----------------
__global__ __launch_bounds__(256) void k_p1(const float* __restrict__ xc,
                                            const float* __restrict__ W1,
                                            const __bf16* __restrict__ W1BTh,
                                            const __bf16* __restrict__ W1BTl,
                                            const float* __restrict__ e1,
                                            const int* __restrict__ loc,
                                            float* __restrict__ pBT,
                                            float* __restrict__ pA,
                                            float* __restrict__ SB1,
                                            float* __restrict__ SB2,
                                            float* __restrict__ SB3) {
  __shared__ float xr[MID_];
  int t = threadIdx.x, lane = t & 63;
  int w = t >> 6;
  int blk = blockIdx.x;
  if (blk < 1024) {
    int nb = blk * 32;
    int q = lane >> 4, li = lane & 15;
    int jt0 = (w == 0) ? 0 : (w == 1) ? 4 : (w == 2) ? 7 : 10;
    int njt = (w == 0) ? 4 : 3;
    f32x4 zero4 = {0.f, 0.f, 0.f, 0.f};
    f32x4 acc0[4], acc1[4];
#pragma unroll
    for (int i = 0; i < 4; i++) { acc0[i] = zero4; acc1[i] = zero4; }
    const float* xr0 = xc + (size_t)(nb + li) * MID_;
    const float* xr1 = xc + (size_t)(nb + 16 + li) * MID_;
    for (int kc = 0; kc < 7; kc++) {
      int k0 = kc * 32 + q * 8;
      bf16x8 b0h, b0l, b1h, b1l;
      if (k0 < MID_) {
        cvt8(xr0 + k0, b0h, b0l);
        cvt8(xr1 + k0, b1h, b1l);
      } else {
#pragma unroll
        for (int i = 0; i < 8; i++) {
          b0h[i] = (__bf16)0.f; b0l[i] = (__bf16)0.f;
          b1h[i] = (__bf16)0.f; b1l[i] = (__bf16)0.f;
        }
      }
#pragma unroll
      for (int jj = 0; jj < 4; jj++) {
        if (jj < njt) {
          int jt = jt0 + jj;
          bf16x8 ah = *(const bf16x8*)(W1BTh + (size_t)(jt * 16 + li) * 224 + k0);
          bf16x8 al = *(const bf16x8*)(W1BTl + (size_t)(jt * 16 + li) * 224 + k0);
          acc0[jj] = mfma16(ah, b0h, acc0[jj]);
          acc0[jj] = mfma16(ah, b0l, acc0[jj]);
          acc0[jj] = mfma16(al, b0h, acc0[jj]);
          acc1[jj] = mfma16(ah, b1h, acc1[jj]);
          acc1[jj] = mfma16(ah, b1l, acc1[jj]);
          acc1[jj] = mfma16(al, b1h, acc1[jj]);
        }
      }
    }
    float ev0 = e1[nb + li];
    float ev1 = e1[nb + 16 + li];
#pragma unroll
    for (int jj = 0; jj < 4; jj++) {
      if (jj < njt) {
        int jt = jt0 + jj;
#pragma unroll
        for (int r = 0; r < 4; r++) {
          int j = jt * 16 + q * 4 + r;
          float* pb = pBT + (size_t)j * NODES + nb + li;
          pb[0] = acc0[jj][r];
          pb[16] = acc1[jj][r];
        }
        float s1v[4], s2v[4], s3v[4];
#pragma unroll
        for (int r = 0; r < 4; r++) {
          float a0 = acc0[jj][r], a1 = acc1[jj][r];
          s1v[r] = a0 + a1;
          s2v[r] = fmaf(a0, a0, a1 * a1);
          s3v[r] = fmaf(a0, ev0, a1 * ev1);
        }
#pragma unroll
        for (int o = 8; o > 0; o >>= 1) {
#pragma unroll
          for (int r = 0; r < 4; r++) {
            s1v[r] += __shfl_xor(s1v[r], o);
            s2v[r] += __shfl_xor(s2v[r], o);
            s3v[r] += __shfl_xor(s3v[r], o);
          }
        }
        if (li < 4) {
          float g1 = (li == 0) ? s1v[0] : (li == 1) ? s1v[1] : (li == 2) ? s1v[2] : s1v[3];
          float g2 = (li == 0) ? s2v[0] : (li == 1) ? s2v[1] : (li == 2) ? s2v[2] : s2v[3];
          float g3 = (li == 0) ? s3v[0] : (li == 1) ? s3v[1] : (li == 2) ? s3v[2] : s3v[3];
          int j = jt * 16 + q * 4 + li;
          SB1[(size_t)blk * MID_ + j] = g1;
          SB2[(size_t)blk * MID_ + j] = g2;
          SB3[(size_t)blk * MID_ + j] = g3;
        }
      }
    }
  } else {
    int ab = blk - 1024;           // b*16 + a
    int b = ab >> 4;
    int node = b * N_ + loc[ab];
    for (int i = t; i < MID_; i += 256) xr[i] = xc[(size_t)node * MID_ + i];
    __syncthreads();
    if (t < MID_) {
      float acc = 0.f;
      for (int i = 0; i < MID_; i++) acc = fmaf(xr[i], W1[i * MID_ + t], acc);
      pA[ab * MID_ + t] = acc;
    }
  }
}

// ---------------- fin: one block per feature j — stats from SB partials + BN finalize + vaT + wpack ----------------
__global__ __launch_bounds__(256) void k_fin(const float* __restrict__ SB1,
                                             const float* __restrict__ SB2,
                                             const float* __restrict__ SB3,
                                             const float* __restrict__ pA,
                                             const float* __restrict__ cu,
                                             const float* __restrict__ base,
                                             const float* __restrict__ d1row,
                                             const float* __restrict__ c2row,
                                             const int* __restrict__ loc,
                                             const float* __restrict__ bng,
                                             const float* __restrict__ bnb,
                                             const float* __restrict__ W2,
                                             float* __restrict__ vaT,
                                             float* __restrict__ wpack4) {
  __shared__ float utmp[1536 + 192];
  __shared__ float redm[4];
  __shared__ float reds[4];
  __shared__ float bcast[2];
  int t = threadIdx.x, lane = t & 63, w = t >> 6;
  int j = blockIdx.x;
  float cuj = cu[j], bj = base[j];
  float q1 = 0.f, q2 = 0.f, q3 = 0.f;
#pragma unroll
  for (int c = t * 4; c < t * 4 + 4; c++) {
    q1 += SB1[(size_t)c * MID_ + j];
    q2 += SB2[(size_t)c * MID_ + j];
    q3 += SB3[(size_t)c * MID_ + j];
  }
  float t1 = 0.f, t2 = 0.f, t3 = 0.f;
#pragma unroll
  for (int r = t * 2; r < t * 2 + 2; r++) {
    float pa = pA[r * MID_ + j] + bj;
    t1 += pa;
    t2 = fmaf(pa, pa, t2);
    t3 = fmaf(pa, d1row[loc[r]], t3);
  }
  utmp[0 * 256 + t] = q1;
  utmp[1 * 256 + t] = q2;
  utmp[2 * 256 + t] = q3;
  utmp[3 * 256 + t] = t1;
  utmp[4 * 256 + t] = t2;
  utmp[5 * 256 + t] = t3;
  float p1 = 0.f, p2 = 0.f;
#pragma unroll
  for (int r = t * 2; r < t * 2 + 2; r++) {
    int l = loc[r];
    p1 += d1row[l];
    p2 += c2row[l];
  }
#pragma unroll
  for (int o = 32; o > 0; o >>= 1) { p1 += __shfl_xor(p1, o); p2 += __shfl_xor(p2, o); }
  if (lane == 0) { redm[w] = p1; reds[w] = p2; }
  __syncthreads();
  if (t < 192) {
    int s = t >> 5, b32 = t & 31;
    float ssum = 0.f;
#pragma unroll
    for (int i = 0; i < 8; i++) ssum += utmp[s * 256 + b32 * 8 + i];
    utmp[1536 + s * 32 + b32] = ssum;
  }
  __syncthreads();
  if (t == 0) {
    float Sc1 = (redm[0] + redm[1]) + (redm[2] + redm[3]);
    float Sc2 = (reds[0] + reds[1]) + (reds[2] + reds[3]);
    double T1 = 0, T2 = 0, T3 = 0, cross = 0, sp1 = 0, sp2 = 0, spe = 0;
    for (int b = 0; b < 32; b++) {
      float sq1 = utmp[1536 + 0 * 32 + b];
      float sq2 = utmp[1536 + 1 * 32 + b];
      float sq3 = utmp[1536 + 2 * 32 + b];
      float pt1 = utmp[1536 + 3 * 32 + b];
      float pt2 = utmp[1536 + 4 * 32 + b];
      float pt3 = utmp[1536 + 5 * 32 + b];
      T1 += pt1; T2 += pt2; T3 += pt3;
      cross += (double)pt1 * sq1;
      sp1 += sq1; sp2 += sq2; spe += sq3;
    }
    double s1 = 1024.0 * T1 + 16.0 * sp1 + (double)cuj * Sc1;
    double s2 = 1024.0 * T2 + 16.0 * sp2 + (double)cuj * cuj * Sc2 +
                2.0 * (cross + (double)cuj * (T3 + spe));
    double mu = s1 * (1.0 / (double)ROWS);
    double var = s2 * (1.0 / (double)ROWS) - mu * mu;
    float sc = (float)(1.0 / sqrt(var + 1e-5)) * bng[j];
    float sh = bnb[j] - (float)mu * sc;
    bcast[0] = sc;
    bcast[1] = sh;
    wpack4[4 * j + 0] = sc;
    wpack4[4 * j + 1] = cuj * sc;
    wpack4[4 * j + 2] = W2[j];
    wpack4[4 * j + 3] = 0.f;
  }
  __syncthreads();
  float sc = bcast[0], sh = bcast[1];
#pragma unroll
  for (int r = t * 2; r < t * 2 + 2; r++) {
    int b = r >> 4, a = r & 15;
    float pa = pA[r * MID_ + j] + bj;
    vaT[((size_t)b * MID_ + j) * 16 + a] = pa * sc + sh;
  }
}

// ---------------- logits: 1024 threads (16 waves x 13 j's) -> 32 waves/CU; single accL pass ----------------
__global__ __launch_bounds__(1024) void k_logits(const float* __restrict__ pBT,
                                                 const float* __restrict__ vaT,
                                                 const float* __restrict__ wpack4,
                                                 const float* __restrict__ dist,
                                                 const int* __restrict__ loc,
                                                 const int* __restrict__ mask,
                                                 const float* __restrict__ b2,
                                                 float* __restrict__ lg,
                                                 float2* __restrict__ Psm) {
  __shared__ float vaS[MID_ * 16];
  __shared__ float accL[16][16][64];
  __shared__ int loc_s[16];
  __shared__ float redm[16];
  __shared__ float reds[16];
  int t = threadIdx.x, lane = t & 63;
  int w = __builtin_amdgcn_readfirstlane(t >> 6);   // 0..15
  int b = blockIdx.y, nt = blockIdx.x;
  int n0 = nt * 64;
  if (t < 16) loc_s[t] = loc[b * 16 + t];
  for (int i = t; i < MID_ * 16; i += 1024) vaS[i] = vaT[(size_t)b * MID_ * 16 + i];
  __syncthreads();
  float c[16];
#pragma unroll
  for (int a = 0; a < 16; a++) c[a] = dist[(size_t)loc_s[a] * N_ + n0 + lane];
  float acc16[16];
#pragma unroll
  for (int a = 0; a < 16; a++) acc16[a] = 0.f;
  const float4* wp = (const float4*)wpack4;
  int ng = b * N_ + n0 + lane;
  int jb = w * 13;
#pragma unroll 2
  for (int jj = 0; jj < 13; jj++) {
    int j = jb + jj;
    float pbv = pBT[(size_t)j * NODES + ng];
    float4 wv = wp[j];
    float pbs = pbv * wv.x;
    const float* va = &vaS[j * 16];
#pragma unroll
    for (int a = 0; a < 16; a++) {
      float h = fmaf(c[a], wv.y, va[a] + pbs);
      h = fmaxf(h, 0.f);
      acc16[a] = fmaf(h, wv.z, acc16[a]);
    }
  }

  // one full-width transpose pass: all 16 agents at once
#pragma unroll
  for (int a = 0; a < 16; a++) accL[w][a][lane] = acc16[a];
  __syncthreads();
  float b2v = b2[0];
  int a = t >> 6, nn = t & 63;     // 1024 threads = 16 agents x 64 nodes
  float s = b2v;
#pragma unroll
  for (int ww = 0; ww < 16; ww++) s += accL[ww][a][nn];
  int oi = b * AN_ + a * N_ + n0 + nn;
  bool m_ = mask[oi] != 0;
  float sv = m_ ? s : -1e8f;

  float mx = sv;
#pragma unroll
  for (int o = 32; o > 0; o >>= 1) mx = fmaxf(mx, __shfl_xor(mx, o));
  if (lane == 0) redm[t >> 6] = mx;
  __syncthreads();
  mx = redm[0];
#pragma unroll
  for (int k = 1; k < 16; k++) mx = fmaxf(mx, redm[k]);
  float pv = m_ ? expf(sv - mx) : 0.f;
  lg[oi] = pv;
  float ssum = pv;
#pragma unroll
  for (int o = 32; o > 0; o >>= 1) ssum += __shfl_xor(ssum, o);
  if (lane == 0) reds[t >> 6] = ssum;
  __syncthreads();
  if (t == 0) {
    float S = 0.f;
#pragma unroll
    for (int k = 0; k < 16; k++) S += reds[k];
    Psm[b * 16 + nt] = make_float2(mx, S);
  }
}

// ---------------- sm2: combine 16 block-partials per batch, normalize ----------------
__global__ __launch_bounds__(256) void k_sm2(const float* __restrict__ lg,
                                             const float2* __restrict__ P,
                                             float* __restrict__ out) {
  __shared__ float scs[16];
  int b = blockIdx.y, x = blockIdx.x, t = threadIdx.x;
  float M = -3.0e38f;
  float2 pr[16];
#pragma unroll
  for (int k = 0; k < 16; k++) {
    pr[k] = P[b * 16 + k];
    M = fmaxf(M, pr[k].x);
  }
  float S = 0.f;
#pragma unroll
  for (int k = 0; k < 16; k++) S += pr[k].y * expf(pr[k].x - M);
  float inv = 1.0f / S;
  if (t < 16) scs[t] = expf(pr[t].x - M) * inv;
  __syncthreads();
  const float* lb = lg + b * AN_ + x * 2048;
  float* ob = out + b * AN_ + x * 2048;
#pragma unroll
  for (int k = 0; k < 8; k++) {
    int i = t + 256 * k;
    int n = (x * 2048 + i) & 1023;
    ob[i] = lb[i] * scs[n >> 6];
  }
}

extern "C" void kernel_launch(void* const* d_in, const int* in_sizes, int n_in,
                              void* d_out, int out_size, void* d_ws, size_t ws_size,
                              hipStream_t stream) {
  const float* gn = (const float*)d_in[0];
  const int* el = (const int*)d_in[1];
  const int* loc = (const int*)d_in[2];
  const int* mask = (const int*)d_in[3];
  const float* dist = (const float*)d_in[4];
  const float* c0W = (const float*)d_in[5];
  const float* c0b = (const float*)d_in[6];
  const float* c0g = (const float*)d_in[7];
  const float* c0be = (const float*)d_in[8];
  const float* c1W = (const float*)d_in[9];
  const float* c1b = (const float*)d_in[10];
  const float* c1g = (const float*)d_in[11];
  const float* c1be = (const float*)d_in[12];
  const float* c2W = (const float*)d_in[13];
  const float* c2b = (const float*)d_in[14];
  const float* c2g = (const float*)d_in[15];
  const float* c2be = (const float*)d_in[16];
  const float* eW = (const float*)d_in[17];
  const float* eb = (const float*)d_in[18];
  const float* W1 = (const float*)d_in[19];
  const float* b1 = (const float*)d_in[20];
  const float* bng = (const float*)d_in[21];
  const float* bnb = (const float*)d_in[22];
  const float* W2 = (const float*)d_in[23];
  const float* b2 = (const float*)d_in[24];
  float* out = (float*)d_out;

  char* p = (char*)d_ws;
  auto alloc = [&](size_t bytes) {
    char* r = p;
    p += (bytes + 255) & ~(size_t)255;
    return r;
  };
  int* counts = (int*)alloc((size_t)NODES * 4);
  int* rowptr = (int*)alloc((size_t)NODES * 4);
  int* ssrc = (int*)alloc((size_t)NEDGE * 4);
  float* xc = (float*)alloc((size_t)NODES * MID_ * 4);
  float* pBT = (float*)alloc((size_t)NODES * MID_ * 4);
  float* pA = (float*)alloc((size_t)512 * MID_ * 4);
  float* cu = (float*)alloc(256 * 4);
  float* base = (float*)alloc(256 * 4);
  float* d1row = (float*)alloc((size_t)N_ * 4);
  float* c2row = (float*)alloc((size_t)N_ * 4);
  float* e1 = (float*)alloc((size_t)B_ * N_ * 4);
  float* vaT = (float*)alloc((size_t)B_ * MID_ * 16 * 4);
  float* wpack4 = (float*)alloc((size_t)MID_ * 4 * 4);
  float* lg = (float*)alloc((size_t)ROWS * 4);
  float2* Psm = (float2*)alloc((size_t)B_ * 16 * 8);
  __bf16* W1BTh = (__bf16*)alloc((size_t)MID_ * 224 * 2);
  __bf16* W1BTl = (__bf16*)alloc((size_t)MID_ * 224 * 2);
  float* SB1 = (float*)alloc((size_t)1024 * MID_ * 4);
  float* SB2 = (float*)alloc((size_t)1024 * MID_ * 4);
  float* SB3 = (float*)alloc((size_t)1024 * MID_ * 4);

  k_front<<<529, 256, 0, stream>>>(el, dist, loc, W1, eW, eb, b1,
                                   rowptr, counts, ssrc, d1row, c2row, e1, cu, base,
                                   W1BTh, W1BTl);

  k_layer<16, true><<<1024, 256, 0, stream>>>(gn, FIN_, 0, xc, 16, rowptr, counts, ssrc, c0W, c0b, c0g, c0be);
  k_layer<64, false><<<1024, 256, 0, stream>>>(xc, MID_, 16, xc, 80, rowptr, counts, ssrc, c1W, c1b, c1g, c1be);
  k_layer<64, false><<<1024, 256, 0, stream>>>(xc, MID_, 80, xc, 144, rowptr, counts, ssrc, c2W, c2b, c2g, c2be);

  k_p1<<<1536, 256, 0, stream>>>(xc, W1, W1BTh, W1BTl, e1, loc, pBT, pA, SB1, SB2, SB3);
  k_fin<<<208, 256, 0, stream>>>(SB1, SB2, SB3, pA, cu, base, d1row, c2row, loc, bng, bnb, W2, vaT, wpack4);

  k_logits<<<dim3(16, 32), 1024, 0, stream>>>(pBT, vaT, wpack4, dist, loc, mask, b2, lg, Psm);
  k_sm2<<<dim3(8, 32), 256, 0, stream>>>(lg, Psm, out);
}